// Round 9
// baseline (423.563 us; speedup 1.0000x reference)
//
#include <hip/hip_runtime.h>
#include <hip/hip_bf16.h>
#include <math.h>

#define N0 4096
#define NM1 8192

// workspace float offsets
#define OFF_U   0            // 65536
#define OFF_XL1 65536
#define OFF_XL2 131072
#define OFF_UL1 196608
#define OFF_UL2 262144
#define OFF_INV 327680       // 4096
#define OFF_PB  331776       // 4*65536
#define OFF_PX  593920       // 8*65536
#define OFF_PU  1118208      // 8*65536
#define OFF_PRS 1642496      // 8*4096

// butterfly reduce-scatter: 2*NV values -> NV, exchanging with lane^d.
template<int NV>
__device__ __forceinline__ void red_scatter(float* v, const int d, const int lane) {
  const bool up = (lane & d) != 0;
  #pragma unroll
  for (int i = 0; i < NV; ++i) {
    float send = up ? v[i] : v[i + NV];
    float recv = __shfl_xor(send, d);
    float keep = up ? v[i + NV] : v[i];
    v[i] = keep + recv;
  }
}

// ---------------------------------------------------------------------------
// pB[s] = B1[rows, m-range(s)] @ x1.  LDS-staged X in 256-row chunks (16 KiB).
// grid 2048 = 512 rg x 4 s; 4 waves x 2 rows/wave; q=lane>>5, ml=lane&31.
// Per-lane m-chain: it 0..15, v 0..3 -> m = s*2048 + it*128 + ml*4 + v
// (identical to rounds 4/7/8 -> bit-identical). VGPR ~42; (256,8) caps 64
// -> 8 blocks/CU = 32 waves/CU.
// ---------------------------------------------------------------------------
__global__ __launch_bounds__(256, 8)
void b1_kernel(const float* __restrict__ A,    // [4096][8192]
               const float* __restrict__ X,    // [8192][16]
               float* __restrict__ pP)         // [4][4096][16]
{
  __shared__ float4 Bs[1024];                  // 256 m x 4 col-blocks, 16 KiB
  const int tid  = threadIdx.x;
  const int wv   = tid >> 6;
  const int lane = tid & 63;
  const int q    = lane >> 5;
  const int ml   = lane & 31;
  const int s    = blockIdx.x & 3;
  const int rg   = blockIdx.x >> 2;       // 0..511
  const int row0 = rg * 8 + wv * 2;
  const int mb   = s * 2048;

  const float* A0 = A + (size_t)row0 * NM1 + mb + ml * 4;
  const float* A1 = A0 + NM1;
  const int j0 = q * 2;
  const int jj = tid & 3;
  const int mt = tid >> 2;                // 0..63

  float acc[16];
  #pragma unroll
  for (int i = 0; i < 16; ++i) acc[i] = 0.0f;

  #pragma unroll 1
  for (int ch = 0; ch < 8; ++ch) {        // 256-row chunks
    __syncthreads();
    #pragma unroll
    for (int k = 0; k < 4; ++k) {
      const int m = mt + 64 * k;
      Bs[(m * 4 + jj) ^ ((m >> 2) & 7)] =
          *(const float4*)(X + (size_t)(mb + ch * 256 + m) * 16 + jj * 4);
    }
    __syncthreads();
    #pragma unroll
    for (int il = 0; il < 2; ++il) {
      const int it = ch * 2 + il;
      const float4 a0 = *(const float4*)(A0 + it * 128);
      const float4 a1 = *(const float4*)(A1 + it * 128);
      #pragma unroll
      for (int v = 0; v < 4; ++v) {
        const int mm = il * 128 + ml * 4 + v;     // local row in chunk
        const int h = (mm >> 2) & 7;
        const float4 b0  = Bs[(mm * 4 + j0) ^ h];
        const float4 b1v = Bs[(mm * 4 + j0 + 1) ^ h];
        const float av0 = (&a0.x)[v];
        const float av1 = (&a1.x)[v];
        acc[0]  += av0 * b0.x;   acc[1]  += av0 * b0.y;
        acc[2]  += av0 * b0.z;   acc[3]  += av0 * b0.w;
        acc[4]  += av0 * b1v.x;  acc[5]  += av0 * b1v.y;
        acc[6]  += av0 * b1v.z;  acc[7]  += av0 * b1v.w;
        acc[8]  += av1 * b0.x;   acc[9]  += av1 * b0.y;
        acc[10] += av1 * b0.z;   acc[11] += av1 * b0.w;
        acc[12] += av1 * b1v.x;  acc[13] += av1 * b1v.y;
        acc[14] += av1 * b1v.z;  acc[15] += av1 * b1v.w;
      }
    }
  }

  // reduce across 32 m-lanes, d-sequence 1,2,4,8,16 (as rounds 4/7/8)
  red_scatter<8>(acc, 1, lane);
  red_scatter<4>(acc, 2, lane);
  red_scatter<2>(acc, 4, lane);
  red_scatter<1>(acc, 8, lane);
  const float tot = acc[0] + __shfl_xor(acc[0], 16);

  if (ml < 16) {
    const int r = ml & 1;
    const int c = 4 * ((ml >> 1) & 1) + 2 * ((ml >> 2) & 1) + ((ml >> 3) & 1);
    pP[(size_t)(s * 65536) + (row0 + r) * 16 + q * 8 + c] = tot;
  }
}

// u = sum of 4 b1 partials (left-assoc, matches rounds 4/7/8)
__global__ void finalize_u_kernel(const float* __restrict__ pP,
                                  float* __restrict__ u) {
  const int idx = blockIdx.x * 256 + threadIdx.x;   // < 65536
  u[idx] = pP[idx] + pP[65536 + idx] + pP[131072 + idx] + pP[196608 + idx];
}

// ---------------------------------------------------------------------------
// pX/pU[s] = L0[rows, m-range(s)] @ {cx, cu} (+rowsum when RS).
// LDS-staged B in 128-row chunks (16 KiB). grid 2048 = 256 rg x 8 s;
// 4 waves x 4 rows/wave; q=lane>>3 (0-3 x-chain, 4-7 u-chain), ml=lane&7.
// m-chain: it 0..15, v 0..3 -> m = s*512 + it*32 + ml*4 + v (bit-identical
// to rounds 4/7/8). VGPR ~50; (256,8) caps 64 -> 8 blocks/CU = 32 waves/CU.
// ---------------------------------------------------------------------------
template<bool RS>
__global__ __launch_bounds__(256, 8)
void cheb_kernel(const float* __restrict__ A,     // [4096][4096]
                 const float* __restrict__ cx,    // [4096][16]
                 const float* __restrict__ cu,    // [4096][16]
                 float* __restrict__ pX,          // [8][4096][16]
                 float* __restrict__ pU,          // [8][4096][16]
                 float* __restrict__ pRS)         // [8][4096]
{
  __shared__ float4 Bs[1024];                  // 128 m x 8 col-blocks, 16 KiB
  const int tid  = threadIdx.x;
  const int wv   = tid >> 6;
  const int lane = tid & 63;
  const int q    = lane >> 3;
  const int ml   = lane & 7;
  const int s    = blockIdx.x & 7;
  const int rg   = blockIdx.x >> 3;       // 0..255
  const int row0 = rg * 16 + wv * 4;
  const int mb   = s * 512;

  const float* Ab = A + (size_t)row0 * N0 + mb + ml * 4;
  const int jj = tid & 7;
  const int mt = tid >> 3;                // 0..31
  const float* sbase = (jj < 4) ? cx : cu;
  const int joff = (jj & 3) * 4;

  float acc[16];
  #pragma unroll
  for (int i = 0; i < 16; ++i) acc[i] = 0.0f;
  float rs[4] = {0.0f, 0.0f, 0.0f, 0.0f};

  #pragma unroll 1
  for (int ch = 0; ch < 4; ++ch) {        // 128-row chunks
    __syncthreads();
    #pragma unroll
    for (int k = 0; k < 4; ++k) {
      const int m = mt + 32 * k;
      Bs[(m * 8 + jj) ^ ((m >> 2) & 7)] =
          *(const float4*)(sbase + (size_t)(mb + ch * 128 + m) * 16 + joff);
    }
    __syncthreads();
    #pragma unroll
    for (int il = 0; il < 4; ++il) {
      const int it = ch * 4 + il;
      float4 b[4];
      #pragma unroll
      for (int v = 0; v < 4; ++v) {
        const int mm = il * 32 + ml * 4 + v;      // local row in chunk
        b[v] = Bs[(mm * 8 + q) ^ ((mm >> 2) & 7)];
      }
      #pragma unroll
      for (int r = 0; r < 4; ++r) {
        const float4 a = *(const float4*)(Ab + (size_t)r * N0 + it * 32);
        #pragma unroll
        for (int v = 0; v < 4; ++v) {
          const float av = (&a.x)[v];
          acc[r*4+0] += av * b[v].x;  acc[r*4+1] += av * b[v].y;
          acc[r*4+2] += av * b[v].z;  acc[r*4+3] += av * b[v].w;
          if constexpr (RS) rs[r] += av;
        }
      }
    }
  }

  // reduce across 8 m-lanes, d-sequence 1,2,4 (as rounds 4/7/8)
  red_scatter<8>(acc, 1, lane);
  red_scatter<4>(acc, 2, lane);
  red_scatter<2>(acc, 4, lane);
  const int r   = 2 * (ml & 1) + ((ml >> 1) & 1);
  const int ch2 = (ml >> 2) & 1;
  float* base = (q >> 2) ? pU : pX;
  *(float2*)(base + (size_t)(s * 65536) + (row0 + r) * 16 + (q & 3) * 4 + ch2 * 2) =
      make_float2(acc[0], acc[1]);

  if constexpr (RS) {
    red_scatter<2>(rs, 1, lane);
    red_scatter<1>(rs, 2, lane);
    const float rsum = rs[0] + __shfl_xor(rs[0], 4);
    if (q == 0 && ml < 4) {
      const int rr = 2 * (ml & 1) + ((ml >> 1) & 1);
      pRS[s * N0 + row0 + rr] = rsum;
    }
  }
}

// ---------------------------------------------------------------------------
// norm1: inv = 1/sum8(pRS) (nonfinite->0); normalize step-1 partials.
// ---------------------------------------------------------------------------
__global__ void norm1_kernel(const float* __restrict__ pX,
                             const float* __restrict__ pU,
                             const float* __restrict__ pRS,
                             float* __restrict__ inv,
                             float* __restrict__ ox,
                             float* __restrict__ ou) {
  const int idx = blockIdx.x * 256 + threadIdx.x;   // < 65536
  const int row = idx >> 4;
  float rsv = 0.0f;
  #pragma unroll
  for (int s2 = 0; s2 < 8; ++s2) rsv += pRS[s2 * N0 + row];
  float iv = 1.0f / rsv;
  if (!isfinite(iv)) iv = 0.0f;
  if ((idx & 15) == 0) inv[row] = iv;
  float xv = 0.0f, uv = 0.0f;
  #pragma unroll
  for (int s2 = 0; s2 < 8; ++s2) { xv += pX[s2*65536 + idx]; uv += pU[s2*65536 + idx]; }
  xv *= iv; uv *= iv;
  ox[idx] = isfinite(xv) ? xv : 0.0f;
  ou[idx] = isfinite(uv) ? uv : 0.0f;
}

__global__ void norm23_kernel(const float* __restrict__ pX,
                              const float* __restrict__ pU,
                              const float* __restrict__ inv,
                              float* __restrict__ ox,
                              float* __restrict__ ou) {
  const int idx = blockIdx.x * 256 + threadIdx.x;   // < 65536
  const float iv = inv[idx >> 4];
  float xv = 0.0f, uv = 0.0f;
  #pragma unroll
  for (int s2 = 0; s2 < 8; ++s2) { xv += pX[s2*65536 + idx]; uv += pU[s2*65536 + idx]; }
  xv *= iv; uv *= iv;
  ox[idx] = isfinite(xv) ? xv : 0.0f;
  ou[idx] = isfinite(uv) ? uv : 0.0f;
}

// ---------------------------------------------------------------------------
// y0[n,o] = sum_{i,k} xall[n,i,k]*W[i,o,k]; k: 0=x0, 1..3=xlap, 4=u, 5..7=ulap.
// k=3,7 (step-3 norm) fused from pX/pU partials.
// ---------------------------------------------------------------------------
__global__ void einsum_kernel(const float* __restrict__ x0,
                              const float* __restrict__ xl1,
                              const float* __restrict__ xl2,
                              const float* __restrict__ u,
                              const float* __restrict__ ul1,
                              const float* __restrict__ ul2,
                              const float* __restrict__ pX,
                              const float* __restrict__ pU,
                              const float* __restrict__ inv,
                              const float* __restrict__ W,   // [16][16][8]
                              float* __restrict__ y) {
  __shared__ float Wl[2048];
  __shared__ float xs[16 * 128];                 // [r][k][i]
  const int t = threadIdx.x;
  const int row0 = blockIdx.x * 16;
  #pragma unroll
  for (int k = 0; k < 8; ++k) Wl[t + 256 * k] = W[t + 256 * k];
  const int r = t >> 4;
  const int i = t & 15;
  const int g = (row0 + r) * 16 + i;
  const float iv = inv[row0 + r];
  float x3 = 0.0f, u3 = 0.0f;
  #pragma unroll
  for (int s2 = 0; s2 < 8; ++s2) { x3 += pX[s2*65536 + g]; u3 += pU[s2*65536 + g]; }
  x3 *= iv; u3 *= iv;
  if (!isfinite(x3)) x3 = 0.0f;
  if (!isfinite(u3)) u3 = 0.0f;
  xs[r*128 + 0*16 + i] = x0[g];
  xs[r*128 + 1*16 + i] = xl1[g];
  xs[r*128 + 2*16 + i] = xl2[g];
  xs[r*128 + 3*16 + i] = x3;
  xs[r*128 + 4*16 + i] = u[g];
  xs[r*128 + 5*16 + i] = ul1[g];
  xs[r*128 + 6*16 + i] = ul2[g];
  xs[r*128 + 7*16 + i] = u3;
  __syncthreads();
  const int o = t & 15;
  float a = 0.0f;
  #pragma unroll
  for (int ii = 0; ii < 16; ++ii) {
    #pragma unroll
    for (int k = 0; k < 8; ++k)
      a += xs[r*128 + k*16 + ii] * Wl[(ii*16 + o)*8 + k];
  }
  y[(row0 + r) * 16 + o] = a;
}

// ---------------------------------------------------------------------------
extern "C" void kernel_launch(void* const* d_in, const int* in_sizes, int n_in,
                              void* d_out, int out_size, void* d_ws, size_t ws_size,
                              hipStream_t stream) {
  (void)in_sizes; (void)n_in; (void)out_size; (void)ws_size;
  const float* x0 = (const float*)d_in[0];
  const float* x1 = (const float*)d_in[1];
  const float* L0 = (const float*)d_in[3];
  const float* B1 = (const float*)d_in[8];
  const float* W0 = (const float*)d_in[10];

  float* ws  = (float*)d_ws;
  float* u   = ws + OFF_U;
  float* xl1 = ws + OFF_XL1;
  float* xl2 = ws + OFF_XL2;
  float* ul1 = ws + OFF_UL1;
  float* ul2 = ws + OFF_UL2;
  float* inv = ws + OFF_INV;
  float* pB  = ws + OFF_PB;
  float* pX  = ws + OFF_PX;
  float* pU  = ws + OFF_PU;
  float* pRS = ws + OFF_PRS;

  // u = b1 @ x_1
  b1_kernel<<<2048, 256, 0, stream>>>(B1, x1, pB);
  finalize_u_kernel<<<256, 256, 0, stream>>>(pB, u);

  // step 1 (computes rowsum -> inv)
  cheb_kernel<true><<<2048, 256, 0, stream>>>(L0, x0, u, pX, pU, pRS);
  norm1_kernel<<<256, 256, 0, stream>>>(pX, pU, pRS, inv, xl1, ul1);
  // step 2
  cheb_kernel<false><<<2048, 256, 0, stream>>>(L0, xl1, ul1, pX, pU, pRS);
  norm23_kernel<<<256, 256, 0, stream>>>(pX, pU, inv, xl2, ul2);
  // step 3 (normalization fused into einsum)
  cheb_kernel<false><<<2048, 256, 0, stream>>>(L0, xl2, ul2, pX, pU, pRS);

  // y_0 = einsum('nik,iok->no', x_0_all, weight_0)
  einsum_kernel<<<256, 256, 0, stream>>>(x0, xl1, xl2, u, ul1, ul2,
                                         pX, pU, inv, W0, (float*)d_out);
}

// Round 10
// 139.669 us; speedup vs baseline: 3.0326x; 3.0326x over previous
//
#include <hip/hip_runtime.h>
#include <hip/hip_bf16.h>
#include <math.h>

#define N0 4096
#define NM1 8192

// workspace float offsets
#define OFF_U   0            // 65536
#define OFF_XL1 65536
#define OFF_XL2 131072
#define OFF_UL1 196608
#define OFF_UL2 262144
#define OFF_INV 327680       // 4096
#define OFF_PB  331776       // 4*65536
#define OFF_PX  593920       // 8*65536
#define OFF_PU  1118208      // 8*65536
#define OFF_PRS 1642496      // 8*4096

// butterfly reduce-scatter: 2*NV values -> NV, exchanging with lane^d.
template<int NV>
__device__ __forceinline__ void red_scatter(float* v, const int d, const int lane) {
  const bool up = (lane & d) != 0;
  #pragma unroll
  for (int i = 0; i < NV; ++i) {
    float send = up ? v[i] : v[i + NV];
    float recv = __shfl_xor(send, d);
    float keep = up ? v[i + NV] : v[i];
    v[i] = keep + recv;
  }
}

// ---------------------------------------------------------------------------
// pB[s] = B1[rows, m-range(s)] @ x1.  LDS-staged X in 256-row chunks (16 KiB).
// grid 2048 = 512 rg x 4 s; 4 waves x 2 rows/wave; q=lane>>5, ml=lane&31.
// Per-lane m-chain: it 0..15, v 0..3 -> m = s*2048 + it*128 + ml*4 + v
// (identical to rounds 4/7/8/9 -> bit-identical).
// NO min-waves clamp: R3/R7/R9 proved any forced waves/EU floor makes the
// allocator under-allocate (32-64 VGPR vs ~50-90 need) and spill to scratch.
// Natural allocation here ~40-45 VGPR -> up to 8 blocks/CU on its own.
// ---------------------------------------------------------------------------
__global__ __launch_bounds__(256)
void b1_kernel(const float* __restrict__ A,    // [4096][8192]
               const float* __restrict__ X,    // [8192][16]
               float* __restrict__ pP)         // [4][4096][16]
{
  __shared__ float4 Bs[1024];                  // 256 m x 4 col-blocks, 16 KiB
  const int tid  = threadIdx.x;
  const int wv   = tid >> 6;
  const int lane = tid & 63;
  const int q    = lane >> 5;
  const int ml   = lane & 31;
  const int s    = blockIdx.x & 3;
  const int rg   = blockIdx.x >> 2;       // 0..511
  const int row0 = rg * 8 + wv * 2;
  const int mb   = s * 2048;

  const float* A0 = A + (size_t)row0 * NM1 + mb + ml * 4;
  const float* A1 = A0 + NM1;
  const int j0 = q * 2;
  const int jj = tid & 3;
  const int mt = tid >> 2;                // 0..63

  float acc[16];
  #pragma unroll
  for (int i = 0; i < 16; ++i) acc[i] = 0.0f;

  #pragma unroll 1
  for (int ch = 0; ch < 8; ++ch) {        // 256-row chunks
    __syncthreads();
    #pragma unroll
    for (int k = 0; k < 4; ++k) {
      const int m = mt + 64 * k;
      Bs[(m * 4 + jj) ^ ((m >> 2) & 7)] =
          *(const float4*)(X + (size_t)(mb + ch * 256 + m) * 16 + jj * 4);
    }
    __syncthreads();
    #pragma unroll
    for (int il = 0; il < 2; ++il) {
      const int it = ch * 2 + il;
      const float4 a0 = *(const float4*)(A0 + it * 128);
      const float4 a1 = *(const float4*)(A1 + it * 128);
      #pragma unroll
      for (int v = 0; v < 4; ++v) {
        const int mm = il * 128 + ml * 4 + v;     // local row in chunk
        const int h = (mm >> 2) & 7;
        const float4 b0  = Bs[(mm * 4 + j0) ^ h];
        const float4 b1v = Bs[(mm * 4 + j0 + 1) ^ h];
        const float av0 = (&a0.x)[v];
        const float av1 = (&a1.x)[v];
        acc[0]  += av0 * b0.x;   acc[1]  += av0 * b0.y;
        acc[2]  += av0 * b0.z;   acc[3]  += av0 * b0.w;
        acc[4]  += av0 * b1v.x;  acc[5]  += av0 * b1v.y;
        acc[6]  += av0 * b1v.z;  acc[7]  += av0 * b1v.w;
        acc[8]  += av1 * b0.x;   acc[9]  += av1 * b0.y;
        acc[10] += av1 * b0.z;   acc[11] += av1 * b0.w;
        acc[12] += av1 * b1v.x;  acc[13] += av1 * b1v.y;
        acc[14] += av1 * b1v.z;  acc[15] += av1 * b1v.w;
      }
    }
  }

  // reduce across 32 m-lanes, d-sequence 1,2,4,8,16 (as rounds 4/7/8/9)
  red_scatter<8>(acc, 1, lane);
  red_scatter<4>(acc, 2, lane);
  red_scatter<2>(acc, 4, lane);
  red_scatter<1>(acc, 8, lane);
  const float tot = acc[0] + __shfl_xor(acc[0], 16);

  if (ml < 16) {
    const int r = ml & 1;
    const int c = 4 * ((ml >> 1) & 1) + 2 * ((ml >> 2) & 1) + ((ml >> 3) & 1);
    pP[(size_t)(s * 65536) + (row0 + r) * 16 + q * 8 + c] = tot;
  }
}

// u = sum of 4 b1 partials (left-assoc, matches rounds 4/7/8/9)
__global__ void finalize_u_kernel(const float* __restrict__ pP,
                                  float* __restrict__ u) {
  const int idx = blockIdx.x * 256 + threadIdx.x;   // < 65536
  u[idx] = pP[idx] + pP[65536 + idx] + pP[131072 + idx] + pP[196608 + idx];
}

// ---------------------------------------------------------------------------
// pX/pU[s] = L0[rows, m-range(s)] @ {cx, cu} (+rowsum when RS).
// LDS-staged B in 128-row chunks (16 KiB). grid 2048 = 256 rg x 8 s;
// 4 waves x 4 rows/wave; q=lane>>3 (0-3 x-chain, 4-7 u-chain), ml=lane&7.
// m-chain: it 0..15, v 0..3 -> m = s*512 + it*32 + ml*4 + v (bit-identical
// to rounds 4/7/8/9). NO min-waves clamp (see b1 note). Natural ~50-60 VGPR.
// ---------------------------------------------------------------------------
template<bool RS>
__global__ __launch_bounds__(256)
void cheb_kernel(const float* __restrict__ A,     // [4096][4096]
                 const float* __restrict__ cx,    // [4096][16]
                 const float* __restrict__ cu,    // [4096][16]
                 float* __restrict__ pX,          // [8][4096][16]
                 float* __restrict__ pU,          // [8][4096][16]
                 float* __restrict__ pRS)         // [8][4096]
{
  __shared__ float4 Bs[1024];                  // 128 m x 8 col-blocks, 16 KiB
  const int tid  = threadIdx.x;
  const int wv   = tid >> 6;
  const int lane = tid & 63;
  const int q    = lane >> 3;
  const int ml   = lane & 7;
  const int s    = blockIdx.x & 7;
  const int rg   = blockIdx.x >> 3;       // 0..255
  const int row0 = rg * 16 + wv * 4;
  const int mb   = s * 512;

  const float* Ab = A + (size_t)row0 * N0 + mb + ml * 4;
  const int jj = tid & 7;
  const int mt = tid >> 3;                // 0..31
  const float* sbase = (jj < 4) ? cx : cu;
  const int joff = (jj & 3) * 4;

  float acc[16];
  #pragma unroll
  for (int i = 0; i < 16; ++i) acc[i] = 0.0f;
  float rs[4] = {0.0f, 0.0f, 0.0f, 0.0f};

  #pragma unroll 1
  for (int ch = 0; ch < 4; ++ch) {        // 128-row chunks
    __syncthreads();
    #pragma unroll
    for (int k = 0; k < 4; ++k) {
      const int m = mt + 32 * k;
      Bs[(m * 8 + jj) ^ ((m >> 2) & 7)] =
          *(const float4*)(sbase + (size_t)(mb + ch * 128 + m) * 16 + joff);
    }
    __syncthreads();
    #pragma unroll
    for (int il = 0; il < 4; ++il) {
      const int it = ch * 4 + il;
      float4 b[4];
      #pragma unroll
      for (int v = 0; v < 4; ++v) {
        const int mm = il * 32 + ml * 4 + v;      // local row in chunk
        b[v] = Bs[(mm * 8 + q) ^ ((mm >> 2) & 7)];
      }
      #pragma unroll
      for (int r = 0; r < 4; ++r) {
        const float4 a = *(const float4*)(Ab + (size_t)r * N0 + it * 32);
        #pragma unroll
        for (int v = 0; v < 4; ++v) {
          const float av = (&a.x)[v];
          acc[r*4+0] += av * b[v].x;  acc[r*4+1] += av * b[v].y;
          acc[r*4+2] += av * b[v].z;  acc[r*4+3] += av * b[v].w;
          if constexpr (RS) rs[r] += av;
        }
      }
    }
  }

  // reduce across 8 m-lanes, d-sequence 1,2,4 (as rounds 4/7/8/9)
  red_scatter<8>(acc, 1, lane);
  red_scatter<4>(acc, 2, lane);
  red_scatter<2>(acc, 4, lane);
  const int r   = 2 * (ml & 1) + ((ml >> 1) & 1);
  const int ch2 = (ml >> 2) & 1;
  float* base = (q >> 2) ? pU : pX;
  *(float2*)(base + (size_t)(s * 65536) + (row0 + r) * 16 + (q & 3) * 4 + ch2 * 2) =
      make_float2(acc[0], acc[1]);

  if constexpr (RS) {
    red_scatter<2>(rs, 1, lane);
    red_scatter<1>(rs, 2, lane);
    const float rsum = rs[0] + __shfl_xor(rs[0], 4);
    if (q == 0 && ml < 4) {
      const int rr = 2 * (ml & 1) + ((ml >> 1) & 1);
      pRS[s * N0 + row0 + rr] = rsum;
    }
  }
}

// ---------------------------------------------------------------------------
// norm1: inv = 1/sum8(pRS) (nonfinite->0); normalize step-1 partials.
// ---------------------------------------------------------------------------
__global__ void norm1_kernel(const float* __restrict__ pX,
                             const float* __restrict__ pU,
                             const float* __restrict__ pRS,
                             float* __restrict__ inv,
                             float* __restrict__ ox,
                             float* __restrict__ ou) {
  const int idx = blockIdx.x * 256 + threadIdx.x;   // < 65536
  const int row = idx >> 4;
  float rsv = 0.0f;
  #pragma unroll
  for (int s2 = 0; s2 < 8; ++s2) rsv += pRS[s2 * N0 + row];
  float iv = 1.0f / rsv;
  if (!isfinite(iv)) iv = 0.0f;
  if ((idx & 15) == 0) inv[row] = iv;
  float xv = 0.0f, uv = 0.0f;
  #pragma unroll
  for (int s2 = 0; s2 < 8; ++s2) { xv += pX[s2*65536 + idx]; uv += pU[s2*65536 + idx]; }
  xv *= iv; uv *= iv;
  ox[idx] = isfinite(xv) ? xv : 0.0f;
  ou[idx] = isfinite(uv) ? uv : 0.0f;
}

__global__ void norm23_kernel(const float* __restrict__ pX,
                              const float* __restrict__ pU,
                              const float* __restrict__ inv,
                              float* __restrict__ ox,
                              float* __restrict__ ou) {
  const int idx = blockIdx.x * 256 + threadIdx.x;   // < 65536
  const float iv = inv[idx >> 4];
  float xv = 0.0f, uv = 0.0f;
  #pragma unroll
  for (int s2 = 0; s2 < 8; ++s2) { xv += pX[s2*65536 + idx]; uv += pU[s2*65536 + idx]; }
  xv *= iv; uv *= iv;
  ox[idx] = isfinite(xv) ? xv : 0.0f;
  ou[idx] = isfinite(uv) ? uv : 0.0f;
}

// ---------------------------------------------------------------------------
// y0[n,o] = sum_{i,k} xall[n,i,k]*W[i,o,k]; k: 0=x0, 1..3=xlap, 4=u, 5..7=ulap.
// k=3,7 (step-3 norm) fused from pX/pU partials.
// ---------------------------------------------------------------------------
__global__ void einsum_kernel(const float* __restrict__ x0,
                              const float* __restrict__ xl1,
                              const float* __restrict__ xl2,
                              const float* __restrict__ u,
                              const float* __restrict__ ul1,
                              const float* __restrict__ ul2,
                              const float* __restrict__ pX,
                              const float* __restrict__ pU,
                              const float* __restrict__ inv,
                              const float* __restrict__ W,   // [16][16][8]
                              float* __restrict__ y) {
  __shared__ float Wl[2048];
  __shared__ float xs[16 * 128];                 // [r][k][i]
  const int t = threadIdx.x;
  const int row0 = blockIdx.x * 16;
  #pragma unroll
  for (int k = 0; k < 8; ++k) Wl[t + 256 * k] = W[t + 256 * k];
  const int r = t >> 4;
  const int i = t & 15;
  const int g = (row0 + r) * 16 + i;
  const float iv = inv[row0 + r];
  float x3 = 0.0f, u3 = 0.0f;
  #pragma unroll
  for (int s2 = 0; s2 < 8; ++s2) { x3 += pX[s2*65536 + g]; u3 += pU[s2*65536 + g]; }
  x3 *= iv; u3 *= iv;
  if (!isfinite(x3)) x3 = 0.0f;
  if (!isfinite(u3)) u3 = 0.0f;
  xs[r*128 + 0*16 + i] = x0[g];
  xs[r*128 + 1*16 + i] = xl1[g];
  xs[r*128 + 2*16 + i] = xl2[g];
  xs[r*128 + 3*16 + i] = x3;
  xs[r*128 + 4*16 + i] = u[g];
  xs[r*128 + 5*16 + i] = ul1[g];
  xs[r*128 + 6*16 + i] = ul2[g];
  xs[r*128 + 7*16 + i] = u3;
  __syncthreads();
  const int o = t & 15;
  float a = 0.0f;
  #pragma unroll
  for (int ii = 0; ii < 16; ++ii) {
    #pragma unroll
    for (int k = 0; k < 8; ++k)
      a += xs[r*128 + k*16 + ii] * Wl[(ii*16 + o)*8 + k];
  }
  y[(row0 + r) * 16 + o] = a;
}

// ---------------------------------------------------------------------------
extern "C" void kernel_launch(void* const* d_in, const int* in_sizes, int n_in,
                              void* d_out, int out_size, void* d_ws, size_t ws_size,
                              hipStream_t stream) {
  (void)in_sizes; (void)n_in; (void)out_size; (void)ws_size;
  const float* x0 = (const float*)d_in[0];
  const float* x1 = (const float*)d_in[1];
  const float* L0 = (const float*)d_in[3];
  const float* B1 = (const float*)d_in[8];
  const float* W0 = (const float*)d_in[10];

  float* ws  = (float*)d_ws;
  float* u   = ws + OFF_U;
  float* xl1 = ws + OFF_XL1;
  float* xl2 = ws + OFF_XL2;
  float* ul1 = ws + OFF_UL1;
  float* ul2 = ws + OFF_UL2;
  float* inv = ws + OFF_INV;
  float* pB  = ws + OFF_PB;
  float* pX  = ws + OFF_PX;
  float* pU  = ws + OFF_PU;
  float* pRS = ws + OFF_PRS;

  // u = b1 @ x_1
  b1_kernel<<<2048, 256, 0, stream>>>(B1, x1, pB);
  finalize_u_kernel<<<256, 256, 0, stream>>>(pB, u);

  // step 1 (computes rowsum -> inv)
  cheb_kernel<true><<<2048, 256, 0, stream>>>(L0, x0, u, pX, pU, pRS);
  norm1_kernel<<<256, 256, 0, stream>>>(pX, pU, pRS, inv, xl1, ul1);
  // step 2
  cheb_kernel<false><<<2048, 256, 0, stream>>>(L0, xl1, ul1, pX, pU, pRS);
  norm23_kernel<<<256, 256, 0, stream>>>(pX, pU, inv, xl2, ul2);
  // step 3 (normalization fused into einsum)
  cheb_kernel<false><<<2048, 256, 0, stream>>>(L0, xl2, ul2, pX, pU, pRS);

  // y_0 = einsum('nik,iok->no', x_0_all, weight_0)
  einsum_kernel<<<256, 256, 0, stream>>>(x0, xl1, xl2, u, ul1, ul2,
                                         pX, pU, inv, W0, (float*)d_out);
}